// Round 2
// baseline (472.165 us; speedup 1.0000x reference)
//
#include <hip/hip_runtime.h>
#include <stdint.h>

typedef unsigned short u16;
typedef unsigned int u32;

#define B_ 16
#define N_ 4096
#define S_ 512
#define D2_ 384
#define K_ 5
#define CIN 387
#define KP 416
#define M_ (B_*N_)

typedef float f32x4 __attribute__((ext_vector_type(4)));
typedef __bf16 bf16x8 __attribute__((ext_vector_type(8)));

__device__ __forceinline__ float bf2f(u16 h) {
  union { u32 u; float f; } v; v.u = ((u32)h) << 16; return v.f;
}
__device__ __forceinline__ u16 f2bf(float f) {
  union { float f; u32 u; } v; v.f = f;
  u32 u = v.u;
  u32 r = (u + 0x7FFFu + ((u >> 16) & 1u)) >> 16;
  return (u16)r;
}

// ---------------- zero scratch stats ----------------
__global__ void zero_kernel(float* __restrict__ p, int nel) {
  int i = blockIdx.x * 256 + threadIdx.x;
  if (i < nel) p[i] = 0.f;
}

// ---------------- pad+convert W0 [384,387] f32 -> [384,416] bf16 ----------------
__global__ void pad_w0_kernel(const float* __restrict__ W0, u16* __restrict__ W0p) {
  int i = blockIdx.x * 256 + threadIdx.x;   // 384*416 = 159744 = 624*256
  int r = i / KP, c = i - r * KP;
  W0p[i] = (c < CIN) ? f2bf(W0[r * CIN + c]) : (u16)0;
}

// ---------------- convert W1 [384,384] f32 -> bf16 ----------------
__global__ void conv_w1_kernel(const float* __restrict__ W1, u16* __restrict__ W1c) {
  int i = blockIdx.x * 256 + threadIdx.x;   // 147456 = 576*256
  W1c[i] = f2bf(W1[i]);
}

// ---------------- KNN + inverse-distance interpolation ----------------
// one wave per query; 4 queries (waves) per block; block stages xyz2[b] in LDS
__global__ __launch_bounds__(256) void knn_interp_kernel(
    const float* __restrict__ xyz1, const float* __restrict__ xyz2,
    const float* __restrict__ points1, const float* __restrict__ points2,
    const int* __restrict__ emb_lens,
    u16* __restrict__ A1, float* __restrict__ idx_out)
{
  __shared__ float sxyz[S_ * 3];
  int b = blockIdx.x >> 10;             // 1024 blocks per batch
  int n0 = (blockIdx.x & 1023) << 2;
  int tid = threadIdx.x;
  for (int i = tid; i < S_ * 3; i += 256) sxyz[i] = xyz2[b * S_ * 3 + i];
  __syncthreads();

  int lane = tid & 63, wid = tid >> 6;
  int n = n0 + wid;
  int L = emb_lens[b];
  const float* q = xyz1 + ((size_t)b * N_ + n) * 3;
  float qx = q[0], qy = q[1], qz = q[2];

  // d2 computed EXACTLY like the numpy reference: no FMA contraction,
  // association (dx*dx + dy*dy) + dz*dz. Required for bitwise-identical
  // distances so top-k tie/order matches the reference's stable top_k.
  float d[8];
  #pragma unroll
  for (int t = 0; t < 8; ++t) {
    int s = t * 64 + lane;
    float dx = __fsub_rn(qx, sxyz[3*s]);
    float dy = __fsub_rn(qy, sxyz[3*s+1]);
    float dz = __fsub_rn(qz, sxyz[3*s+2]);
    float dd = __fadd_rn(__fadd_rn(__fmul_rn(dx,dx), __fmul_rn(dy,dy)),
                         __fmul_rn(dz,dz));
    d[t] = (s < L) ? dd : 1e10f;
  }

  int taken = 0;
  int idxk[K_]; float dk[K_];
  for (int k = 0; k < K_; ++k) {
    float best = 3e38f; int bs = 1 << 30;
    #pragma unroll
    for (int t = 0; t < 8; ++t) {
      if (!(taken & (1 << t))) {
        int s = t * 64 + lane;
        if (d[t] < best || (d[t] == best && s < bs)) { best = d[t]; bs = s; }
      }
    }
    #pragma unroll
    for (int off = 32; off > 0; off >>= 1) {
      float ob = __shfl_xor(best, off);
      int obs  = __shfl_xor(bs, off);
      if (ob < best || (ob == best && obs < bs)) { best = ob; bs = obs; }
    }
    idxk[k] = bs; dk[k] = best;
    if ((bs & 63) == lane) taken |= 1 << (bs >> 6);
  }

  float w[K_]; float wsum = 0.f;
  #pragma unroll
  for (int k = 0; k < K_; ++k) { w[k] = 1.f / (dk[k] + 1.1920929e-7f); wsum += w[k]; }
  float inv = 1.f / wsum;
  #pragma unroll
  for (int k = 0; k < K_; ++k) w[k] *= inv;

  u16* row = A1 + (size_t)(b * N_ + n) * KP;
  const float* p2 = points2 + (size_t)b * S_ * D2_;
  #pragma unroll
  for (int j = 0; j < 6; ++j) {
    int c = lane + j * 64;
    float acc = 0.f;
    #pragma unroll
    for (int k = 0; k < K_; ++k)
      acc += w[k] * p2[(size_t)idxk[k] * D2_ + c];
    row[3 + c] = f2bf(acc);
  }
  if (lane < 3) row[lane] = f2bf(points1[((size_t)b * N_ + n) * 3 + lane]);
  if (lane < KP - CIN) row[CIN + lane] = 0;

  #pragma unroll
  for (int k = 0; k < K_; ++k)
    if (lane == k) idx_out[((size_t)b * N_ + n) * K_ + k] = (float)idxk[k];
}

// ---------------- NT GEMM: C[m,o] = sum_c A[m,c] * W[o,c] ----------------
// 128x128 tile, 256 threads (4 waves, 2x2 of 64x64), MFMA 16x16x32 bf16
template<bool F32OUT>
__global__ __launch_bounds__(256) void gemm_nt_kernel(
    const u16* __restrict__ A, int lda,
    const u16* __restrict__ W, int ldw,
    void* __restrict__ Cv, int ldc, int KT)
{
  __shared__ __align__(16) u16 sA[128 * 32];
  __shared__ __align__(16) u16 sB[128 * 32];
  int tid = threadIdx.x;
  int lane = tid & 63, wid = tid >> 6;
  int m0 = blockIdx.x * 128, n0 = blockIdx.y * 128;
  int wm = (wid & 1) * 64, wn = (wid >> 1) * 64;
  int frow = lane & 15, quad = lane >> 4;

  int srow = tid >> 2, sq = tid & 3;
  const u16* gA = A + (size_t)(m0 + srow) * lda + sq * 8;
  const u16* gB = W + (size_t)(n0 + srow) * ldw + sq * 8;
  size_t strideA = (size_t)64 * lda;
  size_t strideB = (size_t)64 * ldw;
  u16* lA = sA + srow * 32 + sq * 8;
  u16* lB = sB + srow * 32 + sq * 8;

  f32x4 acc[4][4];
  f32x4 zero4 = {0.f, 0.f, 0.f, 0.f};
  #pragma unroll
  for (int i = 0; i < 4; ++i)
    #pragma unroll
    for (int j = 0; j < 4; ++j) acc[i][j] = zero4;

  for (int kt = 0; kt < KT; ++kt) {
    uint4 av0 = *(const uint4*)(gA);
    uint4 av1 = *(const uint4*)(gA + strideA);
    uint4 bv0 = *(const uint4*)(gB);
    uint4 bv1 = *(const uint4*)(gB + strideB);
    __syncthreads();
    *(uint4*)lA = av0;
    *(uint4*)(lA + 64 * 32) = av1;
    *(uint4*)lB = bv0;
    *(uint4*)(lB + 64 * 32) = bv1;
    __syncthreads();
    bf16x8 af[4], bfr[4];
    #pragma unroll
    for (int i = 0; i < 4; ++i)
      af[i] = *(const bf16x8*)(sA + (wm + i * 16 + frow) * 32 + quad * 8);
    #pragma unroll
    for (int j = 0; j < 4; ++j)
      bfr[j] = *(const bf16x8*)(sB + (wn + j * 16 + frow) * 32 + quad * 8);
    #pragma unroll
    for (int i = 0; i < 4; ++i)
      #pragma unroll
      for (int j = 0; j < 4; ++j)
        acc[i][j] = __builtin_amdgcn_mfma_f32_16x16x32_bf16(af[i], bfr[j], acc[i][j], 0, 0, 0);
    gA += 32; gB += 32;
  }

  // epilogue: C/D layout col=lane&15, row=(lane>>4)*4+reg
  #pragma unroll
  for (int i = 0; i < 4; ++i) {
    #pragma unroll
    for (int j = 0; j < 4; ++j) {
      int col = n0 + wn + j * 16 + frow;
      #pragma unroll
      for (int r = 0; r < 4; ++r) {
        int m = m0 + wm + i * 16 + quad * 4 + r;
        if constexpr (F32OUT) {
          ((float*)Cv)[(size_t)m * ldc + col] = acc[i][j][r];
        } else {
          ((u16*)Cv)[(size_t)m * ldc + col] = f2bf(acc[i][j][r]);
        }
      }
    }
  }
}

// ---------------- masked per-channel sum / sumsq ----------------
__device__ __forceinline__ float ldx(const u16* p)   { return bf2f(*p); }
__device__ __forceinline__ float ldx(const float* p) { return *p; }

template<typename T>
__global__ __launch_bounds__(384) void stats_kernel(
    const T* __restrict__ X, const int* __restrict__ lens,
    float* __restrict__ sums)   // [0..383]=sum, [384..767]=sumsq
{
  int c = threadIdx.x;
  int r0 = blockIdx.x * 256;          // 256 rows per block; never crosses batch
  int b = r0 >> 12;
  int len = lens[b];
  int nbase = r0 & 4095;
  float s = 0.f, q = 0.f;
  for (int i = 0; i < 256; ++i) {
    float v = ldx(X + (size_t)(r0 + i) * D2_ + c);
    if (nbase + i < len) { s += v; q += v * v; }
  }
  atomicAdd(&sums[c], s);
  atomicAdd(&sums[384 + c], q);
}

// ---------------- BN finalize: per-channel scale/shift ----------------
__global__ void bn_finalize_kernel(const float* __restrict__ sums,
    const float* __restrict__ gamma, const float* __restrict__ beta,
    const int* __restrict__ lens, float* __restrict__ par)
{
  int c = threadIdx.x;  // 384
  float nv = 0.f;
  for (int b = 0; b < B_; ++b) nv += (float)lens[b];
  float mean = sums[c] / nv;
  float var = sums[384 + c] / nv - mean * mean;
  var = fmaxf(var, 0.f);
  float rstd = rsqrtf(var + 1e-5f);
  float a = rstd * gamma[c];
  par[c] = a;
  par[384 + c] = beta[c] - mean * a;
}

// ---------------- apply BN + GELU (in place on bf16 x0, masked) ----------------
__global__ __launch_bounds__(256) void apply_bn_gelu_kernel(
    u16* __restrict__ X, const float* __restrict__ par,
    const int* __restrict__ lens)
{
  int chunk = blockIdx.x * 256 + threadIdx.x;  // 65536*48 chunks of 8
  int row = chunk / 48;
  int c0 = (chunk - row * 48) * 8;
  int b = row >> 12, n = row & 4095;
  bool valid = n < lens[b];
  uint4 v = *(uint4*)(X + (size_t)row * D2_ + c0);
  u16* h = (u16*)&v;
  uint4 o;
  u16* ho = (u16*)&o;
  #pragma unroll
  for (int t = 0; t < 8; ++t) {
    float x = bf2f(h[t]);
    int c = c0 + t;
    float y = x * par[c] + par[384 + c];
    float g = 0.5f * y * (1.f + erff(y * 0.70710678118654752f));
    ho[t] = valid ? f2bf(g) : (u16)0;
  }
  *(uint4*)(X + (size_t)row * D2_ + c0) = o;
}

// ---------------- apply BN (masked, in place on f32 out) ----------------
__global__ __launch_bounds__(256) void apply_bn_out_kernel(
    float* __restrict__ X, const float* __restrict__ par,
    const int* __restrict__ lens)
{
  int chunk = blockIdx.x * 256 + threadIdx.x;  // 65536*96 chunks of 4
  int row = chunk / 96;
  int c0 = (chunk - row * 96) * 4;
  int b = row >> 12, n = row & 4095;
  bool valid = n < lens[b];
  float4 v = *(float4*)(X + (size_t)row * D2_ + c0);
  float* h = (float*)&v;
  float4 o;
  float* ho = (float*)&o;
  #pragma unroll
  for (int t = 0; t < 4; ++t) {
    int c = c0 + t;
    float y = h[t] * par[c] + par[384 + c];
    ho[t] = valid ? y : 0.f;
  }
  *(float4*)(X + (size_t)row * D2_ + c0) = o;
}

extern "C" void kernel_launch(void* const* d_in, const int* in_sizes, int n_in,
                              void* d_out, int out_size, void* d_ws, size_t ws_size,
                              hipStream_t stream) {
  const float* xyz1    = (const float*)d_in[0];
  const float* xyz2    = (const float*)d_in[1];
  const float* points1 = (const float*)d_in[2];
  const float* points2 = (const float*)d_in[3];
  const int* point_lens = (const int*)d_in[4];
  const int* emb_lens   = (const int*)d_in[5];
  // d_in[6] = point_mask (recomputed from point_lens)
  const float* W0 = (const float*)d_in[7];
  const float* g0 = (const float*)d_in[8];
  const float* b0 = (const float*)d_in[9];
  const float* W1 = (const float*)d_in[10];
  const float* g1 = (const float*)d_in[11];
  const float* b1 = (const float*)d_in[12];

  float* out = (float*)d_out;
  float* idx_out = out + (size_t)M_ * D2_;   // idx tail (ints as floats)

  char* w = (char*)d_ws;
  u16* A1    = (u16*)w;                       // 65536 x 416 bf16 = 54,525,952 B
  u16* W0p   = (u16*)(w + 54525952);          // 384 x 416 bf16   =    319,488 B
  u16* W1c   = (u16*)(w + 54845440);          // 384 x 384 bf16   =    294,912 B
  u16* x0    = (u16*)(w + 55140352);          // 65536 x 384 bf16 = 50,331,648 B
  float* stats = (float*)(w + 105472000);     // 1536 f32
  float* par   = (float*)(w + 105478144);     // 1536 f32

  zero_kernel<<<6, 256, 0, stream>>>(stats, 1536);
  pad_w0_kernel<<<624, 256, 0, stream>>>(W0, W0p);
  conv_w1_kernel<<<576, 256, 0, stream>>>(W1, W1c);
  knn_interp_kernel<<<16384, 256, 0, stream>>>(xyz1, xyz2, points1, points2,
                                               emb_lens, A1, idx_out);
  gemm_nt_kernel<false><<<dim3(512, 3), 256, 0, stream>>>(A1, KP, W0p, KP, x0, D2_, 13);
  stats_kernel<u16><<<256, 384, 0, stream>>>(x0, point_lens, stats);
  bn_finalize_kernel<<<1, 384, 0, stream>>>(stats, g0, b0, point_lens, par);
  apply_bn_gelu_kernel<<<12288, 256, 0, stream>>>(x0, par, point_lens);
  gemm_nt_kernel<true><<<dim3(512, 3), 256, 0, stream>>>(x0, D2_, W1c, D2_, out, D2_, 12);
  stats_kernel<float><<<256, 384, 0, stream>>>(out, point_lens, stats + 768);
  bn_finalize_kernel<<<1, 384, 0, stream>>>(stats + 768, g1, b1, point_lens, par + 768);
  apply_bn_out_kernel<<<24576, 256, 0, stream>>>(out, par + 768, point_lens);
}

// Round 3
// 465.687 us; speedup vs baseline: 1.0139x; 1.0139x over previous
//
#include <hip/hip_runtime.h>
#include <stdint.h>

typedef unsigned short u16;
typedef unsigned int u32;

#define B_ 16
#define N_ 4096
#define S_ 512
#define D2_ 384
#define K_ 5
#define CIN 387
#define KP 416
#define M_ (B_*N_)

typedef float f32x4 __attribute__((ext_vector_type(4)));
typedef __bf16 bf16x8 __attribute__((ext_vector_type(8)));

__device__ __forceinline__ float bf2f(u16 h) {
  union { u32 u; float f; } v; v.u = ((u32)h) << 16; return v.f;
}
__device__ __forceinline__ u16 f2bf(float f) {
  union { float f; u32 u; } v; v.f = f;
  u32 u = v.u;
  u32 r = (u + 0x7FFFu + ((u >> 16) & 1u)) >> 16;
  return (u16)r;
}

// async global->LDS 16B copy (lane i lands at ldsbase + i*16)
__device__ __forceinline__ void gld16(const void* g, void* l) {
  __builtin_amdgcn_global_load_lds(
      (const __attribute__((address_space(1))) unsigned int*)g,
      (__attribute__((address_space(3))) unsigned int*)l, 16, 0, 0);
}

// ---------------- zero scratch stats ----------------
__global__ void zero_kernel(float* __restrict__ p, int nel) {
  int i = blockIdx.x * 256 + threadIdx.x;
  if (i < nel) p[i] = 0.f;
}

// ---------------- pad+convert W0 [384,387] f32 -> [384,416] bf16 ----------------
__global__ void pad_w0_kernel(const float* __restrict__ W0, u16* __restrict__ W0p) {
  int i = blockIdx.x * 256 + threadIdx.x;   // 384*416 = 159744 = 624*256
  int r = i / KP, c = i - r * KP;
  W0p[i] = (c < CIN) ? f2bf(W0[r * CIN + c]) : (u16)0;
}

// ---------------- convert W1 [384,384] f32 -> bf16 ----------------
__global__ void conv_w1_kernel(const float* __restrict__ W1, u16* __restrict__ W1c) {
  int i = blockIdx.x * 256 + threadIdx.x;   // 147456 = 576*256
  W1c[i] = f2bf(W1[i]);
}

// ---------------- KNN (thread-per-query, chunked) + interpolation ----------------
// block = 128 queries x 2 key-chunks of 256; then block-cooperative interp
__global__ __launch_bounds__(256) void knn_interp_kernel(
    const float* __restrict__ xyz1, const float* __restrict__ xyz2,
    const float* __restrict__ points1, const float* __restrict__ points2,
    const int* __restrict__ emb_lens,
    u16* __restrict__ A1, float* __restrict__ idx_out)
{
  __shared__ float4 sxyz[S_];     // 8 KB
  __shared__ float sd[256][K_];   // 5 KB
  __shared__ int   si[256][K_];   // 5 KB
  __shared__ float sw[128][K_];   // 2.5 KB
  __shared__ int   smi[128][K_];  // 2.5 KB

  int b = blockIdx.x >> 5;              // 32 blocks per batch
  int n0 = (blockIdx.x & 31) << 7;      // 128 queries per block
  int tid = threadIdx.x;

  const float* kb = xyz2 + (size_t)b * S_ * 3;
  for (int i = tid; i < S_; i += 256)
    sxyz[i] = make_float4(kb[3*i], kb[3*i+1], kb[3*i+2], 0.f);
  __syncthreads();

  int L = emb_lens[b];
  int q = tid & 127, chunk = tid >> 7;  // chunk is wave-uniform
  const float* qp = xyz1 + ((size_t)b * N_ + n0 + q) * 3;
  float qx = qp[0], qy = qp[1], qz = qp[2];

  float d0=3e38f, d1=3e38f, d2=3e38f, d3=3e38f, d4=3e38f;
  int   i0=0, i1=0, i2=0, i3=0, i4=0;
  int sbase = chunk << 8;
  #pragma unroll 4
  for (int t = 0; t < 256; ++t) {
    int s = sbase + t;
    float4 k4 = sxyz[s];
    // exact numpy association, no FMA contraction -> bitwise-identical d2
    float dx = __fsub_rn(qx, k4.x), dy = __fsub_rn(qy, k4.y), dz = __fsub_rn(qz, k4.z);
    float dd = __fadd_rn(__fadd_rn(__fmul_rn(dx,dx), __fmul_rn(dy,dy)),
                         __fmul_rn(dz,dz));
    if (s >= L) dd = 1e10f;
    if (dd < d4) {                        // strict < keeps stable (lowest-index) ties
      if (dd < d3) { d4=d3; i4=i3;
        if (dd < d2) { d3=d2; i3=i2;
          if (dd < d1) { d2=d1; i2=i1;
            if (dd < d0) { d1=d0; i1=i0; d0=dd; i0=s; }
            else         { d1=dd; i1=s; }
          } else { d2=dd; i2=s; }
        } else { d3=dd; i3=s; }
      } else { d4=dd; i4=s; }
    }
  }
  sd[tid][0]=d0; sd[tid][1]=d1; sd[tid][2]=d2; sd[tid][3]=d3; sd[tid][4]=d4;
  si[tid][0]=i0; si[tid][1]=i1; si[tid][2]=i2; si[tid][3]=i3; si[tid][4]=i4;
  __syncthreads();

  if (tid < 128) {
    // merge two sorted 5-lists; chunk0 (lower indices) wins ties
    float md[K_]; int mi[K_];
    int pa = 0, pb = 0;
    #pragma unroll
    for (int k = 0; k < K_; ++k) {
      float da_ = sd[tid][pa], db_ = sd[tid + 128][pb];
      bool ta = da_ <= db_;
      md[k] = ta ? da_ : db_;
      mi[k] = ta ? si[tid][pa] : si[tid + 128][pb];
      pa += ta ? 1 : 0; pb += ta ? 0 : 1;
    }
    float w[K_]; float ws = 0.f;
    #pragma unroll
    for (int k = 0; k < K_; ++k) { w[k] = 1.f / (md[k] + 1.1920929e-7f); ws += w[k]; }
    float inv = 1.f / ws;
    size_t row = (size_t)b * N_ + n0 + tid;
    #pragma unroll
    for (int k = 0; k < K_; ++k) {
      sw[tid][k] = w[k] * inv;
      smi[tid][k] = mi[k];
      idx_out[row * K_ + k] = (float)mi[k];
    }
    // A1 row prefix (points1) + zero pad
    u16* rp = A1 + row * KP;
    const float* p1 = points1 + row * 3;
    rp[0] = f2bf(p1[0]); rp[1] = f2bf(p1[1]); rp[2] = f2bf(p1[2]);
    #pragma unroll
    for (int c = CIN; c < KP; ++c) rp[c] = 0;
  }
  __syncthreads();

  // interpolation: coalesced over channels
  const float* p2 = points2 + (size_t)b * S_ * D2_;
  #pragma unroll 1
  for (int pass = 0; pass < 2; ++pass) {
    int c = pass == 0 ? tid : 256 + tid;
    if (c < D2_) {
      for (int qq = 0; qq < 128; ++qq) {
        float acc = 0.f;
        #pragma unroll
        for (int k = 0; k < K_; ++k)
          acc += sw[qq][k] * p2[(size_t)smi[qq][k] * D2_ + c];
        A1[((size_t)b * N_ + n0 + qq) * KP + 3 + c] = f2bf(acc);
      }
    }
  }
}

// ---------------- NT GEMM + fused masked BN stats ----------------
// 128x128 tile, 256 threads (4 waves, 2x2 of 64x64), MFMA 16x16x32 bf16,
// global_load_lds width-16 staging. Each 128-row block lies in ONE batch.
template<bool F32OUT>
__global__ __launch_bounds__(256) void gemm_nt_kernel(
    const u16* __restrict__ A, int lda,
    const u16* __restrict__ W, int ldw,
    void* __restrict__ Cv, int ldc, int KT,
    const int* __restrict__ lens, float* __restrict__ sums)
{
  __shared__ __align__(16) u16 sA[128 * 32];
  __shared__ __align__(16) u16 sB[128 * 32];
  __shared__ float lsum[128], lsq[128];
  int tid = threadIdx.x;
  int lane = tid & 63, wid = tid >> 6;
  int m0 = blockIdx.x * 128, n0 = blockIdx.y * 128;
  int wm = (wid & 1) * 64, wn = (wid >> 1) * 64;
  int frow = lane & 15, quad = lane >> 4;

  if (tid < 128) { lsum[tid] = 0.f; lsq[tid] = 0.f; }

  // wave wid stages row-groups wid and wid+4 of both tiles
  int grow = wid * 16 + (lane >> 2);
  int cq = (lane & 3) * 8;
  const u16* gA0 = A + (size_t)(m0 + grow) * lda + cq;
  const u16* gA1 = gA0 + (size_t)64 * lda;
  const u16* gB0 = W + (size_t)(n0 + grow) * ldw + cq;
  const u16* gB1 = gB0 + (size_t)64 * ldw;
  u16* lA0 = sA + wid * 512;            // wave-uniform LDS bases, 1024 B apart
  u16* lA1 = sA + (wid + 4) * 512;
  u16* lB0 = sB + wid * 512;
  u16* lB1 = sB + (wid + 4) * 512;

  f32x4 acc[4][4];
  f32x4 zero4 = {0.f, 0.f, 0.f, 0.f};
  #pragma unroll
  for (int i = 0; i < 4; ++i)
    #pragma unroll
    for (int j = 0; j < 4; ++j) acc[i][j] = zero4;

  for (int kt = 0; kt < KT; ++kt) {
    __syncthreads();
    gld16(gA0, lA0); gld16(gA1, lA1);
    gld16(gB0, lB0); gld16(gB1, lB1);
    gA0 += 32; gA1 += 32; gB0 += 32; gB1 += 32;
    __syncthreads();
    bf16x8 af[4], bfr[4];
    #pragma unroll
    for (int i = 0; i < 4; ++i)
      af[i] = *(const bf16x8*)(sA + (wm + i * 16 + frow) * 32 + quad * 8);
    #pragma unroll
    for (int j = 0; j < 4; ++j)
      bfr[j] = *(const bf16x8*)(sB + (wn + j * 16 + frow) * 32 + quad * 8);
    #pragma unroll
    for (int i = 0; i < 4; ++i)
      #pragma unroll
      for (int j = 0; j < 4; ++j)
        acc[i][j] = __builtin_amdgcn_mfma_f32_16x16x32_bf16(af[i], bfr[j], acc[i][j], 0, 0, 0);
  }

  // epilogue: C/D layout col=lane&15, row=(lane>>4)*4+reg
  int len = lens[m0 >> 12];             // block never crosses a batch boundary
  float colS[4] = {0,0,0,0}, colQ[4] = {0,0,0,0};
  #pragma unroll
  for (int i = 0; i < 4; ++i) {
    #pragma unroll
    for (int j = 0; j < 4; ++j) {
      int col = n0 + wn + j * 16 + frow;
      #pragma unroll
      for (int r = 0; r < 4; ++r) {
        int m = m0 + wm + i * 16 + quad * 4 + r;
        float v = acc[i][j][r];
        if constexpr (F32OUT) ((float*)Cv)[(size_t)m * ldc + col] = v;
        else                  ((u16*)Cv)[(size_t)m * ldc + col] = f2bf(v);
        float x = ((m & 4095) < len) ? v : 0.f;
        colS[j] += x; colQ[j] += x * x;
      }
    }
  }
  #pragma unroll
  for (int j = 0; j < 4; ++j) {
    colS[j] += __shfl_xor(colS[j], 16); colS[j] += __shfl_xor(colS[j], 32);
    colQ[j] += __shfl_xor(colQ[j], 16); colQ[j] += __shfl_xor(colQ[j], 32);
    if (lane < 16) {
      int cl = wn + j * 16 + frow;
      atomicAdd(&lsum[cl], colS[j]);
      atomicAdd(&lsq[cl], colQ[j]);
    }
  }
  __syncthreads();
  if (tid < 128) {
    atomicAdd(&sums[n0 + tid], lsum[tid]);
    atomicAdd(&sums[384 + n0 + tid], lsq[tid]);
  }
}

// ---------------- BN finalize: per-channel scale/shift ----------------
__global__ void bn_finalize_kernel(const float* __restrict__ sums,
    const float* __restrict__ gamma, const float* __restrict__ beta,
    const int* __restrict__ lens, float* __restrict__ par)
{
  int c = threadIdx.x;  // 384
  float nv = 0.f;
  for (int b = 0; b < B_; ++b) nv += (float)lens[b];
  float mean = sums[c] / nv;
  float var = sums[384 + c] / nv - mean * mean;
  var = fmaxf(var, 0.f);
  float rstd = rsqrtf(var + 1e-5f);
  float a = rstd * gamma[c];
  par[c] = a;
  par[384 + c] = beta[c] - mean * a;
}

// ---------------- apply BN + GELU (in place on bf16 x0, masked) ----------------
__global__ __launch_bounds__(256) void apply_bn_gelu_kernel(
    u16* __restrict__ X, const float* __restrict__ par,
    const int* __restrict__ lens)
{
  int chunk = blockIdx.x * 256 + threadIdx.x;  // 65536*48 chunks of 8
  int row = chunk / 48;
  int c0 = (chunk - row * 48) * 8;
  int b = row >> 12, n = row & 4095;
  bool valid = n < lens[b];
  uint4 v = *(uint4*)(X + (size_t)row * D2_ + c0);
  u16* h = (u16*)&v;
  uint4 o;
  u16* ho = (u16*)&o;
  #pragma unroll
  for (int t = 0; t < 8; ++t) {
    float x = bf2f(h[t]);
    int c = c0 + t;
    float y = x * par[c] + par[384 + c];
    float g = 0.5f * y * (1.f + erff(y * 0.70710678118654752f));
    ho[t] = valid ? f2bf(g) : (u16)0;
  }
  *(uint4*)(X + (size_t)row * D2_ + c0) = o;
}

// ---------------- apply BN (masked, in place on f32 out) ----------------
__global__ __launch_bounds__(256) void apply_bn_out_kernel(
    float* __restrict__ X, const float* __restrict__ par,
    const int* __restrict__ lens)
{
  int chunk = blockIdx.x * 256 + threadIdx.x;  // 65536*96 chunks of 4
  int row = chunk / 96;
  int c0 = (chunk - row * 96) * 4;
  int b = row >> 12, n = row & 4095;
  bool valid = n < lens[b];
  float4 v = *(float4*)(X + (size_t)row * D2_ + c0);
  float* h = (float*)&v;
  float4 o;
  float* ho = (float*)&o;
  #pragma unroll
  for (int t = 0; t < 4; ++t) {
    int c = c0 + t;
    float y = h[t] * par[c] + par[384 + c];
    ho[t] = valid ? y : 0.f;
  }
  *(float4*)(X + (size_t)row * D2_ + c0) = o;
}

extern "C" void kernel_launch(void* const* d_in, const int* in_sizes, int n_in,
                              void* d_out, int out_size, void* d_ws, size_t ws_size,
                              hipStream_t stream) {
  const float* xyz1    = (const float*)d_in[0];
  const float* xyz2    = (const float*)d_in[1];
  const float* points1 = (const float*)d_in[2];
  const float* points2 = (const float*)d_in[3];
  const int* point_lens = (const int*)d_in[4];
  const int* emb_lens   = (const int*)d_in[5];
  // d_in[6] = point_mask (recomputed from point_lens)
  const float* W0 = (const float*)d_in[7];
  const float* g0 = (const float*)d_in[8];
  const float* b0 = (const float*)d_in[9];
  const float* W1 = (const float*)d_in[10];
  const float* g1 = (const float*)d_in[11];
  const float* b1 = (const float*)d_in[12];

  float* out = (float*)d_out;
  float* idx_out = out + (size_t)M_ * D2_;   // idx tail (ints as floats)

  char* w = (char*)d_ws;
  u16* A1    = (u16*)w;                       // 65536 x 416 bf16 = 54,525,952 B
  u16* W0p   = (u16*)(w + 54525952);          // 384 x 416 bf16   =    319,488 B
  u16* W1c   = (u16*)(w + 54845440);          // 384 x 384 bf16   =    294,912 B
  u16* x0    = (u16*)(w + 55140352);          // 65536 x 384 bf16 = 50,331,648 B
  float* stats = (float*)(w + 105472000);     // 1536 f32
  float* par   = (float*)(w + 105478144);     // 1536 f32

  zero_kernel<<<6, 256, 0, stream>>>(stats, 1536);
  pad_w0_kernel<<<624, 256, 0, stream>>>(W0, W0p);
  conv_w1_kernel<<<576, 256, 0, stream>>>(W1, W1c);
  knn_interp_kernel<<<512, 256, 0, stream>>>(xyz1, xyz2, points1, points2,
                                             emb_lens, A1, idx_out);
  gemm_nt_kernel<false><<<dim3(512, 3), 256, 0, stream>>>(
      A1, KP, W0p, KP, x0, D2_, 13, point_lens, stats);
  bn_finalize_kernel<<<1, 384, 0, stream>>>(stats, g0, b0, point_lens, par);
  apply_bn_gelu_kernel<<<12288, 256, 0, stream>>>(x0, par, point_lens);
  gemm_nt_kernel<true><<<dim3(512, 3), 256, 0, stream>>>(
      x0, D2_, W1c, D2_, out, D2_, 12, point_lens, stats + 768);
  bn_finalize_kernel<<<1, 384, 0, stream>>>(stats + 768, g1, b1, point_lens, par + 768);
  apply_bn_out_kernel<<<24576, 256, 0, stream>>>(out, par + 768, point_lens);
}

// Round 4
// 400.237 us; speedup vs baseline: 1.1797x; 1.1635x over previous
//
#include <hip/hip_runtime.h>
#include <stdint.h>

typedef unsigned short u16;
typedef unsigned int u32;

#define B_ 16
#define N_ 4096
#define S_ 512
#define D2_ 384
#define K_ 5
#define CIN 387
#define KP 416
#define M_ (B_*N_)

typedef float f32x4 __attribute__((ext_vector_type(4)));
typedef __bf16 bf16x8 __attribute__((ext_vector_type(8)));

__device__ __forceinline__ float bf2f(u16 h) {
  union { u32 u; float f; } v; v.u = ((u32)h) << 16; return v.f;
}
__device__ __forceinline__ u16 f2bf(float f) {
  union { float f; u32 u; } v; v.f = f;
  u32 u = v.u;
  u32 r = (u + 0x7FFFu + ((u >> 16) & 1u)) >> 16;
  return (u16)r;
}

// async global->LDS 16B copy (lane i lands at ldsbase + i*16)
__device__ __forceinline__ void gld16(const void* g, void* l) {
  __builtin_amdgcn_global_load_lds(
      (const __attribute__((address_space(1))) unsigned int*)g,
      (__attribute__((address_space(3))) unsigned int*)l, 16, 0, 0);
}

// ---------------- zero scratch stats ----------------
__global__ void zero_kernel(float* __restrict__ p, int nel) {
  int i = blockIdx.x * 256 + threadIdx.x;
  if (i < nel) p[i] = 0.f;
}

// ---------------- pad+convert W0 [384,387] f32 -> [384,416] bf16 ----------------
__global__ void pad_w0_kernel(const float* __restrict__ W0, u16* __restrict__ W0p) {
  int i = blockIdx.x * 256 + threadIdx.x;   // 384*416 = 159744 = 624*256
  int r = i / KP, c = i - r * KP;
  W0p[i] = (c < CIN) ? f2bf(W0[r * CIN + c]) : (u16)0;
}

// ---------------- convert W1 [384,384] f32 -> bf16 ----------------
__global__ void conv_w1_kernel(const float* __restrict__ W1, u16* __restrict__ W1c) {
  int i = blockIdx.x * 256 + threadIdx.x;   // 147456 = 576*256
  W1c[i] = f2bf(W1[i]);
}

// ---------------- KNN only (thread-per-query, 2 key-chunks) ----------------
// block = 128 queries x 2 chunks of 256 keys; merge; write weights+indices
__global__ __launch_bounds__(256) void knn_kernel(
    const float* __restrict__ xyz1, const float* __restrict__ xyz2,
    const float* __restrict__ points1, const int* __restrict__ emb_lens,
    u16* __restrict__ A1, float* __restrict__ idx_out,
    float* __restrict__ wq, int* __restrict__ iq)
{
  __shared__ float4 sxyz[S_];     // 8 KB
  __shared__ float sd[256][K_];   // 5 KB
  __shared__ int   si[256][K_];   // 5 KB

  int b = blockIdx.x >> 5;              // 32 blocks per batch
  int n0 = (blockIdx.x & 31) << 7;      // 128 queries per block
  int tid = threadIdx.x;

  const float* kb = xyz2 + (size_t)b * S_ * 3;
  for (int i = tid; i < S_; i += 256)
    sxyz[i] = make_float4(kb[3*i], kb[3*i+1], kb[3*i+2], 0.f);
  __syncthreads();

  int L = emb_lens[b];
  int q = tid & 127, chunk = tid >> 7;  // chunk is wave-uniform
  const float* qp = xyz1 + ((size_t)b * N_ + n0 + q) * 3;
  float qx = qp[0], qy = qp[1], qz = qp[2];

  float d0=3e38f, d1=3e38f, d2=3e38f, d3=3e38f, d4=3e38f;
  int   i0=0, i1=0, i2=0, i3=0, i4=0;
  int sbase = chunk << 8;
  #pragma unroll 4
  for (int t = 0; t < 256; ++t) {
    int s = sbase + t;
    float4 k4 = sxyz[s];
    // exact numpy association, no FMA contraction -> bitwise-identical d2
    float dx = __fsub_rn(qx, k4.x), dy = __fsub_rn(qy, k4.y), dz = __fsub_rn(qz, k4.z);
    float dd = __fadd_rn(__fadd_rn(__fmul_rn(dx,dx), __fmul_rn(dy,dy)),
                         __fmul_rn(dz,dz));
    if (s >= L) dd = 1e10f;
    if (dd < d4) {                        // strict < keeps stable (lowest-index) ties
      if (dd < d3) { d4=d3; i4=i3;
        if (dd < d2) { d3=d2; i3=i2;
          if (dd < d1) { d2=d1; i2=i1;
            if (dd < d0) { d1=d0; i1=i0; d0=dd; i0=s; }
            else         { d1=dd; i1=s; }
          } else { d2=dd; i2=s; }
        } else { d3=dd; i3=s; }
      } else { d4=dd; i4=s; }
    }
  }
  sd[tid][0]=d0; sd[tid][1]=d1; sd[tid][2]=d2; sd[tid][3]=d3; sd[tid][4]=d4;
  si[tid][0]=i0; si[tid][1]=i1; si[tid][2]=i2; si[tid][3]=i3; si[tid][4]=i4;
  __syncthreads();

  if (tid < 128) {
    // merge two sorted 5-lists; chunk0 (lower indices) wins ties
    float md[K_]; int mi[K_];
    int pa = 0, pb = 0;
    #pragma unroll
    for (int k = 0; k < K_; ++k) {
      float da_ = sd[tid][pa], db_ = sd[tid + 128][pb];
      bool ta = da_ <= db_;
      md[k] = ta ? da_ : db_;
      mi[k] = ta ? si[tid][pa] : si[tid + 128][pb];
      pa += ta ? 1 : 0; pb += ta ? 0 : 1;
    }
    float w[K_]; float ws = 0.f;
    #pragma unroll
    for (int k = 0; k < K_; ++k) { w[k] = 1.f / (md[k] + 1.1920929e-7f); ws += w[k]; }
    float inv = 1.f / ws;
    size_t row = (size_t)b * N_ + n0 + tid;
    #pragma unroll
    for (int k = 0; k < K_; ++k) {
      wq[row * K_ + k] = w[k] * inv;
      iq[row * K_ + k] = mi[k];
      idx_out[row * K_ + k] = (float)mi[k];
    }
    // A1 row prefix (points1) + zero pad
    u16* rp = A1 + row * KP;
    const float* p1 = points1 + row * 3;
    rp[0] = f2bf(p1[0]); rp[1] = f2bf(p1[1]); rp[2] = f2bf(p1[2]);
    #pragma unroll
    for (int c = CIN; c < KP; ++c) rp[c] = 0;
  }
}

// ---------------- interpolation: one wave per query ----------------
// XCD-swizzled so each XCD's L2 sees only 2 batches of points2 (1.6 MB < 4 MB)
__global__ __launch_bounds__(256) void interp_kernel(
    const float* __restrict__ points2,
    const float* __restrict__ wq, const int* __restrict__ iq,
    u16* __restrict__ A1)
{
  int lane = threadIdx.x & 63, wid = threadIdx.x >> 6;
  int i = blockIdx.x;                                  // 16384 blocks
  int gq = ((i & 7) << 13) + ((i >> 3) << 2) + wid;    // wave-uniform query id
  int b = gq >> 12;

  float w[K_]; int id[K_];
  #pragma unroll
  for (int k = 0; k < K_; ++k) {
    w[k] = wq[(size_t)gq * K_ + k];      // same addr across wave -> broadcast
    id[k] = iq[(size_t)gq * K_ + k];
  }
  const float* p2 = points2 + (size_t)b * S_ * D2_;
  const float* r0 = p2 + (size_t)id[0] * D2_;
  const float* r1 = p2 + (size_t)id[1] * D2_;
  const float* r2 = p2 + (size_t)id[2] * D2_;
  const float* r3 = p2 + (size_t)id[3] * D2_;
  const float* r4 = p2 + (size_t)id[4] * D2_;
  u16* rp = A1 + (size_t)gq * KP + 3;
  #pragma unroll
  for (int j = 0; j < 6; ++j) {
    int c = j * 64 + lane;
    float acc = w[0]*r0[c] + w[1]*r1[c] + w[2]*r2[c] + w[3]*r3[c] + w[4]*r4[c];
    rp[c] = f2bf(acc);
  }
}

// ---------------- NT GEMM + fused masked BN stats ----------------
// 128x128 tile, 256 threads (4 waves, 2x2 of 64x64), MFMA 16x16x32 bf16,
// global_load_lds width-16 staging, double-buffered LDS (prefetch issued
// AFTER the barrier so it overlaps this tile's MFMA), XCD-aware swizzle:
// 3 n-tiles of one m-tile run consecutively on the SAME XCD -> A-tile L2 hit.
template<bool F32OUT>
__global__ __launch_bounds__(256) void gemm_nt_kernel(
    const u16* __restrict__ A, int lda,
    const u16* __restrict__ W, int ldw,
    void* __restrict__ Cv, int ldc, int KT,
    const int* __restrict__ lens, float* __restrict__ sums)
{
  __shared__ __align__(16) u16 sA[2][128 * 32];
  __shared__ __align__(16) u16 sB[2][128 * 32];
  __shared__ float lsum[128], lsq[128];
  int tid = threadIdx.x;
  int lane = tid & 63, wid = tid >> 6;
  u32 bi = blockIdx.x;                  // 1536 = 512 m-tiles x 3 n-tiles
  u32 s = bi >> 3;                      // [0,192)
  int m0 = (int)(((bi & 7) * 64 + s / 3) * 128);
  int n0 = (int)((s % 3) * 128);
  int wm = (wid & 1) * 64, wn = (wid >> 1) * 64;
  int frow = lane & 15, quad = lane >> 4;

  if (tid < 128) { lsum[tid] = 0.f; lsq[tid] = 0.f; }

  // wave wid stages row-groups wid and wid+4 of both tiles
  int grow = wid * 16 + (lane >> 2);
  int cq = (lane & 3) * 8;
  const u16* gA0 = A + (size_t)(m0 + grow) * lda + cq;
  const u16* gA1 = gA0 + (size_t)64 * lda;
  const u16* gB0 = W + (size_t)(n0 + grow) * ldw + cq;
  const u16* gB1 = gB0 + (size_t)64 * ldw;

  f32x4 acc[4][4];
  f32x4 zero4 = {0.f, 0.f, 0.f, 0.f};
  #pragma unroll
  for (int i = 0; i < 4; ++i)
    #pragma unroll
    for (int j = 0; j < 4; ++j) acc[i][j] = zero4;

  // prologue: stage tile 0 into buffer 0
  gld16(gA0, sA[0] + wid * 512); gld16(gA1, sA[0] + (wid + 4) * 512);
  gld16(gB0, sB[0] + wid * 512); gld16(gB1, sB[0] + (wid + 4) * 512);
  gA0 += 32; gA1 += 32; gB0 += 32; gB1 += 32;

  for (int kt = 0; kt < KT; ++kt) {
    __syncthreads();                    // drains staging of buf kt&1
    int p = kt & 1;
    if (kt + 1 < KT) {                  // prefetch next tile into other buffer
      int np = p ^ 1;
      gld16(gA0, sA[np] + wid * 512); gld16(gA1, sA[np] + (wid + 4) * 512);
      gld16(gB0, sB[np] + wid * 512); gld16(gB1, sB[np] + (wid + 4) * 512);
      gA0 += 32; gA1 += 32; gB0 += 32; gB1 += 32;
    }
    bf16x8 af[4], bfr[4];
    #pragma unroll
    for (int i = 0; i < 4; ++i)
      af[i] = *(const bf16x8*)(sA[p] + (wm + i * 16 + frow) * 32 + quad * 8);
    #pragma unroll
    for (int j = 0; j < 4; ++j)
      bfr[j] = *(const bf16x8*)(sB[p] + (wn + j * 16 + frow) * 32 + quad * 8);
    #pragma unroll
    for (int i = 0; i < 4; ++i)
      #pragma unroll
      for (int j = 0; j < 4; ++j)
        acc[i][j] = __builtin_amdgcn_mfma_f32_16x16x32_bf16(af[i], bfr[j], acc[i][j], 0, 0, 0);
  }

  // epilogue: C/D layout col=lane&15, row=(lane>>4)*4+reg
  int len = lens[m0 >> 12];             // block never crosses a batch boundary
  float colS[4] = {0,0,0,0}, colQ[4] = {0,0,0,0};
  #pragma unroll
  for (int i = 0; i < 4; ++i) {
    #pragma unroll
    for (int j = 0; j < 4; ++j) {
      int col = n0 + wn + j * 16 + frow;
      #pragma unroll
      for (int r = 0; r < 4; ++r) {
        int m = m0 + wm + i * 16 + quad * 4 + r;
        float v = acc[i][j][r];
        if constexpr (F32OUT) ((float*)Cv)[(size_t)m * ldc + col] = v;
        else                  ((u16*)Cv)[(size_t)m * ldc + col] = f2bf(v);
        float x = ((m & 4095) < len) ? v : 0.f;
        colS[j] += x; colQ[j] += x * x;
      }
    }
  }
  #pragma unroll
  for (int j = 0; j < 4; ++j) {
    colS[j] += __shfl_xor(colS[j], 16); colS[j] += __shfl_xor(colS[j], 32);
    colQ[j] += __shfl_xor(colQ[j], 16); colQ[j] += __shfl_xor(colQ[j], 32);
    if (lane < 16) {
      int cl = wn + j * 16 + frow;
      atomicAdd(&lsum[cl], colS[j]);
      atomicAdd(&lsq[cl], colQ[j]);
    }
  }
  __syncthreads();
  if (tid < 128) {
    atomicAdd(&sums[n0 + tid], lsum[tid]);
    atomicAdd(&sums[384 + n0 + tid], lsq[tid]);
  }
}

// ---------------- BN finalize: per-channel scale/shift ----------------
__global__ void bn_finalize_kernel(const float* __restrict__ sums,
    const float* __restrict__ gamma, const float* __restrict__ beta,
    const int* __restrict__ lens, float* __restrict__ par)
{
  int c = threadIdx.x;  // 384
  float nv = 0.f;
  for (int b = 0; b < B_; ++b) nv += (float)lens[b];
  float mean = sums[c] / nv;
  float var = sums[384 + c] / nv - mean * mean;
  var = fmaxf(var, 0.f);
  float rstd = rsqrtf(var + 1e-5f);
  float a = rstd * gamma[c];
  par[c] = a;
  par[384 + c] = beta[c] - mean * a;
}

// ---------------- apply BN + GELU (in place on bf16 x0, masked) ----------------
__global__ __launch_bounds__(256) void apply_bn_gelu_kernel(
    u16* __restrict__ X, const float* __restrict__ par,
    const int* __restrict__ lens)
{
  int chunk = blockIdx.x * 256 + threadIdx.x;  // 65536*48 chunks of 8
  int row = chunk / 48;
  int c0 = (chunk - row * 48) * 8;
  int b = row >> 12, n = row & 4095;
  bool valid = n < lens[b];
  uint4 v = *(uint4*)(X + (size_t)row * D2_ + c0);
  u16* h = (u16*)&v;
  uint4 o;
  u16* ho = (u16*)&o;
  #pragma unroll
  for (int t = 0; t < 8; ++t) {
    float x = bf2f(h[t]);
    int c = c0 + t;
    float y = x * par[c] + par[384 + c];
    float g = 0.5f * y * (1.f + erff(y * 0.70710678118654752f));
    ho[t] = valid ? f2bf(g) : (u16)0;
  }
  *(uint4*)(X + (size_t)row * D2_ + c0) = o;
}

// ---------------- apply BN (masked): bf16 x1 -> f32 out ----------------
__global__ __launch_bounds__(256) void apply_bn_out_kernel(
    const u16* __restrict__ X, const float* __restrict__ par,
    const int* __restrict__ lens, float* __restrict__ out)
{
  int chunk = blockIdx.x * 256 + threadIdx.x;  // 65536*48 chunks of 8
  int row = chunk / 48;
  int c0 = (chunk - row * 48) * 8;
  int b = row >> 12, n = row & 4095;
  bool valid = n < lens[b];
  uint4 v = *(const uint4*)(X + (size_t)row * D2_ + c0);
  u16* h = (u16*)&v;
  float4 o0, o1;
  float* ho = (float*)&o0;   // o0,o1 contiguous via separate stores
  float tmp[8];
  #pragma unroll
  for (int t = 0; t < 8; ++t) {
    float x = bf2f(h[t]);
    int c = c0 + t;
    float y = x * par[c] + par[384 + c];
    tmp[t] = valid ? y : 0.f;
  }
  o0 = make_float4(tmp[0], tmp[1], tmp[2], tmp[3]);
  o1 = make_float4(tmp[4], tmp[5], tmp[6], tmp[7]);
  float* op = out + (size_t)row * D2_ + c0;
  *(float4*)op = o0;
  *(float4*)(op + 4) = o1;
  (void)ho;
}

extern "C" void kernel_launch(void* const* d_in, const int* in_sizes, int n_in,
                              void* d_out, int out_size, void* d_ws, size_t ws_size,
                              hipStream_t stream) {
  const float* xyz1    = (const float*)d_in[0];
  const float* xyz2    = (const float*)d_in[1];
  const float* points1 = (const float*)d_in[2];
  const float* points2 = (const float*)d_in[3];
  const int* point_lens = (const int*)d_in[4];
  const int* emb_lens   = (const int*)d_in[5];
  // d_in[6] = point_mask (recomputed from point_lens)
  const float* W0 = (const float*)d_in[7];
  const float* g0 = (const float*)d_in[8];
  const float* b0 = (const float*)d_in[9];
  const float* W1 = (const float*)d_in[10];
  const float* g1 = (const float*)d_in[11];
  const float* b1 = (const float*)d_in[12];

  float* out = (float*)d_out;
  float* idx_out = out + (size_t)M_ * D2_;   // idx tail (ints as floats)

  char* w = (char*)d_ws;
  u16* A1    = (u16*)w;                       // 65536 x 416 bf16 = 54,525,952 B
  u16* x1    = (u16*)w;                       // overlays A1 (dead after gemm1)
  u16* W0p   = (u16*)(w + 54525952);          // 384 x 416 bf16   =    319,488 B
  u16* W1c   = (u16*)(w + 54845440);          // 384 x 384 bf16   =    294,912 B
  u16* x0    = (u16*)(w + 55140352);          // 65536 x 384 bf16 = 50,331,648 B
  // wq/iq overlay x0 region (both dead before gemm1 writes x0)
  float* wq  = (float*)(w + 55140352);        // 65536 x 5 f32 = 1,310,720 B
  int*   iq  = (int*)(w + 56451072);          // 65536 x 5 i32 = 1,310,720 B
  float* stats = (float*)(w + 105472000);     // 1536 f32
  float* par   = (float*)(w + 105478144);     // 1536 f32

  zero_kernel<<<6, 256, 0, stream>>>(stats, 1536);
  pad_w0_kernel<<<624, 256, 0, stream>>>(W0, W0p);
  conv_w1_kernel<<<576, 256, 0, stream>>>(W1, W1c);
  knn_kernel<<<512, 256, 0, stream>>>(xyz1, xyz2, points1, emb_lens,
                                      A1, idx_out, wq, iq);
  interp_kernel<<<16384, 256, 0, stream>>>(points2, wq, iq, A1);
  gemm_nt_kernel<false><<<1536, 256, 0, stream>>>(
      A1, KP, W0p, KP, x0, D2_, 13, point_lens, stats);
  bn_finalize_kernel<<<1, 384, 0, stream>>>(stats, g0, b0, point_lens, par);
  apply_bn_gelu_kernel<<<12288, 256, 0, stream>>>(x0, par, point_lens);
  gemm_nt_kernel<false><<<1536, 256, 0, stream>>>(
      x0, D2_, W1c, D2_, x1, D2_, 12, point_lens, stats + 768);
  bn_finalize_kernel<<<1, 384, 0, stream>>>(stats + 768, g1, b1, point_lens, par + 768);
  apply_bn_out_kernel<<<12288, 256, 0, stream>>>(x1, par + 768, point_lens, out);
}

// Round 5
// 396.308 us; speedup vs baseline: 1.1914x; 1.0099x over previous
//
#include <hip/hip_runtime.h>
#include <stdint.h>

typedef unsigned short u16;
typedef unsigned int u32;

#define B_ 16
#define N_ 4096
#define S_ 512
#define D2_ 384
#define K_ 5
#define CIN 387
#define KP 416
#define M_ (B_*N_)

typedef float f32x4 __attribute__((ext_vector_type(4)));
typedef __bf16 bf16x8 __attribute__((ext_vector_type(8)));

__device__ __forceinline__ float bf2f(u16 h) {
  union { u32 u; float f; } v; v.u = ((u32)h) << 16; return v.f;
}
__device__ __forceinline__ u16 f2bf(float f) {
  union { float f; u32 u; } v; v.f = f;
  u32 u = v.u;
  u32 r = (u + 0x7FFFu + ((u >> 16) & 1u)) >> 16;
  return (u16)r;
}

// Branch-free erf, Abramowitz-Stegun 7.1.26: |err| <= 1.5e-7 absolute.
// Replaces ocml erff (branchy, div-sequence, latency-chain-bound).
__device__ __forceinline__ float erf_approx(float x) {
  float ax = fabsf(x);
  float t = __builtin_amdgcn_rcpf(fmaf(0.3275911f, ax, 1.0f));
  float p = fmaf(t, 1.061405429f, -1.453152027f);
  p = fmaf(p, t, 1.421413741f);
  p = fmaf(p, t, -0.284496736f);
  p = fmaf(p, t, 0.254829592f);
  p = p * t;
  float e = __expf(-ax * ax);
  float r = fmaf(-p, e, 1.0f);
  return copysignf(r, x);
}

// async global->LDS 16B copy (lane i lands at ldsbase + i*16)
__device__ __forceinline__ void gld16(const void* g, void* l) {
  __builtin_amdgcn_global_load_lds(
      (const __attribute__((address_space(1))) unsigned int*)g,
      (__attribute__((address_space(3))) unsigned int*)l, 16, 0, 0);
}

// ---------------- zero scratch stats ----------------
__global__ void zero_kernel(float* __restrict__ p, int nel) {
  int i = blockIdx.x * 256 + threadIdx.x;
  if (i < nel) p[i] = 0.f;
}

// ---------------- pad+convert W0 [384,387] f32 -> [384,416] bf16 ----------------
__global__ void pad_w0_kernel(const float* __restrict__ W0, u16* __restrict__ W0p) {
  int i = blockIdx.x * 256 + threadIdx.x;   // 384*416 = 159744 = 624*256
  int r = i / KP, c = i - r * KP;
  W0p[i] = (c < CIN) ? f2bf(W0[r * CIN + c]) : (u16)0;
}

// ---------------- convert W1 [384,384] f32 -> bf16 ----------------
__global__ void conv_w1_kernel(const float* __restrict__ W1, u16* __restrict__ W1c) {
  int i = blockIdx.x * 256 + threadIdx.x;   // 147456 = 576*256
  W1c[i] = f2bf(W1[i]);
}

// ---------------- KNN only (thread-per-query, 2 key-chunks) ----------------
__global__ __launch_bounds__(256) void knn_kernel(
    const float* __restrict__ xyz1, const float* __restrict__ xyz2,
    const float* __restrict__ points1, const int* __restrict__ emb_lens,
    u16* __restrict__ A1, float* __restrict__ idx_out,
    float* __restrict__ wq, int* __restrict__ iq)
{
  __shared__ float4 sxyz[S_];     // 8 KB
  __shared__ float sd[256][K_];   // 5 KB
  __shared__ int   si[256][K_];   // 5 KB

  int b = blockIdx.x >> 5;              // 32 blocks per batch
  int n0 = (blockIdx.x & 31) << 7;      // 128 queries per block
  int tid = threadIdx.x;

  const float* kb = xyz2 + (size_t)b * S_ * 3;
  for (int i = tid; i < S_; i += 256)
    sxyz[i] = make_float4(kb[3*i], kb[3*i+1], kb[3*i+2], 0.f);
  __syncthreads();

  int L = emb_lens[b];
  int q = tid & 127, chunk = tid >> 7;  // chunk is wave-uniform
  const float* qp = xyz1 + ((size_t)b * N_ + n0 + q) * 3;
  float qx = qp[0], qy = qp[1], qz = qp[2];

  float d0=3e38f, d1=3e38f, d2=3e38f, d3=3e38f, d4=3e38f;
  int   i0=0, i1=0, i2=0, i3=0, i4=0;
  int sbase = chunk << 8;
  #pragma unroll 4
  for (int t = 0; t < 256; ++t) {
    int s = sbase + t;
    float4 k4 = sxyz[s];
    // exact numpy association, no FMA contraction -> bitwise-identical d2
    float dx = __fsub_rn(qx, k4.x), dy = __fsub_rn(qy, k4.y), dz = __fsub_rn(qz, k4.z);
    float dd = __fadd_rn(__fadd_rn(__fmul_rn(dx,dx), __fmul_rn(dy,dy)),
                         __fmul_rn(dz,dz));
    if (s >= L) dd = 1e10f;
    if (dd < d4) {                        // strict < keeps stable (lowest-index) ties
      if (dd < d3) { d4=d3; i4=i3;
        if (dd < d2) { d3=d2; i3=i2;
          if (dd < d1) { d2=d1; i2=i1;
            if (dd < d0) { d1=d0; i1=i0; d0=dd; i0=s; }
            else         { d1=dd; i1=s; }
          } else { d2=dd; i2=s; }
        } else { d3=dd; i3=s; }
      } else { d4=dd; i4=s; }
    }
  }
  sd[tid][0]=d0; sd[tid][1]=d1; sd[tid][2]=d2; sd[tid][3]=d3; sd[tid][4]=d4;
  si[tid][0]=i0; si[tid][1]=i1; si[tid][2]=i2; si[tid][3]=i3; si[tid][4]=i4;
  __syncthreads();

  if (tid < 128) {
    // merge two sorted 5-lists; chunk0 (lower indices) wins ties
    float md[K_]; int mi[K_];
    int pa = 0, pb = 0;
    #pragma unroll
    for (int k = 0; k < K_; ++k) {
      float da_ = sd[tid][pa], db_ = sd[tid + 128][pb];
      bool ta = da_ <= db_;
      md[k] = ta ? da_ : db_;
      mi[k] = ta ? si[tid][pa] : si[tid + 128][pb];
      pa += ta ? 1 : 0; pb += ta ? 0 : 1;
    }
    float w[K_]; float ws = 0.f;
    #pragma unroll
    for (int k = 0; k < K_; ++k) { w[k] = 1.f / (md[k] + 1.1920929e-7f); ws += w[k]; }
    float inv = 1.f / ws;
    size_t row = (size_t)b * N_ + n0 + tid;
    #pragma unroll
    for (int k = 0; k < K_; ++k) {
      wq[row * K_ + k] = w[k] * inv;
      iq[row * K_ + k] = mi[k];
      idx_out[row * K_ + k] = (float)mi[k];
    }
    // A1 row prefix (points1) + zero pad
    u16* rp = A1 + row * KP;
    const float* p1 = points1 + row * 3;
    rp[0] = f2bf(p1[0]); rp[1] = f2bf(p1[1]); rp[2] = f2bf(p1[2]);
    #pragma unroll
    for (int c = CIN; c < KP; ++c) rp[c] = 0;
  }
}

// ---------------- interpolation: one wave per query ----------------
// XCD-swizzled so each XCD's L2 sees only 2 batches of points2 (1.6 MB < 4 MB)
__global__ __launch_bounds__(256) void interp_kernel(
    const float* __restrict__ points2,
    const float* __restrict__ wq, const int* __restrict__ iq,
    u16* __restrict__ A1)
{
  int lane = threadIdx.x & 63, wid = threadIdx.x >> 6;
  int i = blockIdx.x;                                  // 16384 blocks
  int gq = ((i & 7) << 13) + ((i >> 3) << 2) + wid;    // wave-uniform query id
  int b = gq >> 12;

  float w[K_]; int id[K_];
  #pragma unroll
  for (int k = 0; k < K_; ++k) {
    w[k] = wq[(size_t)gq * K_ + k];      // same addr across wave -> broadcast
    id[k] = iq[(size_t)gq * K_ + k];
  }
  const float* p2 = points2 + (size_t)b * S_ * D2_;
  const float* r0 = p2 + (size_t)id[0] * D2_;
  const float* r1 = p2 + (size_t)id[1] * D2_;
  const float* r2 = p2 + (size_t)id[2] * D2_;
  const float* r3 = p2 + (size_t)id[3] * D2_;
  const float* r4 = p2 + (size_t)id[4] * D2_;
  u16* rp = A1 + (size_t)gq * KP + 3;
  #pragma unroll
  for (int j = 0; j < 6; ++j) {
    int c = j * 64 + lane;
    float acc = w[0]*r0[c] + w[1]*r1[c] + w[2]*r2[c] + w[3]*r3[c] + w[4]*r4[c];
    rp[c] = f2bf(acc);
  }
}

// ---------------- NT GEMM + fused masked BN stats ----------------
// 128x128 tile, 256 threads (4 waves, 2x2 of 64x64), MFMA 16x16x32 bf16,
// global_load_lds width-16 staging, double-buffered LDS, XCD-aware swizzle.
template<bool F32OUT>
__global__ __launch_bounds__(256) void gemm_nt_kernel(
    const u16* __restrict__ A, int lda,
    const u16* __restrict__ W, int ldw,
    void* __restrict__ Cv, int ldc, int KT,
    const int* __restrict__ lens, float* __restrict__ sums)
{
  __shared__ __align__(16) u16 sA[2][128 * 32];
  __shared__ __align__(16) u16 sB[2][128 * 32];
  __shared__ float lsum[128], lsq[128];
  int tid = threadIdx.x;
  int lane = tid & 63, wid = tid >> 6;
  u32 bi = blockIdx.x;                  // 1536 = 512 m-tiles x 3 n-tiles
  u32 s = bi >> 3;                      // [0,192)
  int m0 = (int)(((bi & 7) * 64 + s / 3) * 128);
  int n0 = (int)((s % 3) * 128);
  int wm = (wid & 1) * 64, wn = (wid >> 1) * 64;
  int frow = lane & 15, quad = lane >> 4;

  if (tid < 128) { lsum[tid] = 0.f; lsq[tid] = 0.f; }

  // wave wid stages row-groups wid and wid+4 of both tiles
  int grow = wid * 16 + (lane >> 2);
  int cq = (lane & 3) * 8;
  const u16* gA0 = A + (size_t)(m0 + grow) * lda + cq;
  const u16* gA1 = gA0 + (size_t)64 * lda;
  const u16* gB0 = W + (size_t)(n0 + grow) * ldw + cq;
  const u16* gB1 = gB0 + (size_t)64 * ldw;

  f32x4 acc[4][4];
  f32x4 zero4 = {0.f, 0.f, 0.f, 0.f};
  #pragma unroll
  for (int i = 0; i < 4; ++i)
    #pragma unroll
    for (int j = 0; j < 4; ++j) acc[i][j] = zero4;

  // prologue: stage tile 0 into buffer 0
  gld16(gA0, sA[0] + wid * 512); gld16(gA1, sA[0] + (wid + 4) * 512);
  gld16(gB0, sB[0] + wid * 512); gld16(gB1, sB[0] + (wid + 4) * 512);
  gA0 += 32; gA1 += 32; gB0 += 32; gB1 += 32;

  for (int kt = 0; kt < KT; ++kt) {
    __syncthreads();                    // drains staging of buf kt&1
    int p = kt & 1;
    if (kt + 1 < KT) {                  // prefetch next tile into other buffer
      int np = p ^ 1;
      gld16(gA0, sA[np] + wid * 512); gld16(gA1, sA[np] + (wid + 4) * 512);
      gld16(gB0, sB[np] + wid * 512); gld16(gB1, sB[np] + (wid + 4) * 512);
      gA0 += 32; gA1 += 32; gB0 += 32; gB1 += 32;
    }
    bf16x8 af[4], bfr[4];
    #pragma unroll
    for (int i = 0; i < 4; ++i)
      af[i] = *(const bf16x8*)(sA[p] + (wm + i * 16 + frow) * 32 + quad * 8);
    #pragma unroll
    for (int j = 0; j < 4; ++j)
      bfr[j] = *(const bf16x8*)(sB[p] + (wn + j * 16 + frow) * 32 + quad * 8);
    #pragma unroll
    for (int i = 0; i < 4; ++i)
      #pragma unroll
      for (int j = 0; j < 4; ++j)
        acc[i][j] = __builtin_amdgcn_mfma_f32_16x16x32_bf16(af[i], bfr[j], acc[i][j], 0, 0, 0);
  }

  // epilogue: C/D layout col=lane&15, row=(lane>>4)*4+reg
  int len = lens[m0 >> 12];             // block never crosses a batch boundary
  float colS[4] = {0,0,0,0}, colQ[4] = {0,0,0,0};
  #pragma unroll
  for (int i = 0; i < 4; ++i) {
    #pragma unroll
    for (int j = 0; j < 4; ++j) {
      int col = n0 + wn + j * 16 + frow;
      #pragma unroll
      for (int r = 0; r < 4; ++r) {
        int m = m0 + wm + i * 16 + quad * 4 + r;
        float v = acc[i][j][r];
        if constexpr (F32OUT) ((float*)Cv)[(size_t)m * ldc + col] = v;
        else                  ((u16*)Cv)[(size_t)m * ldc + col] = f2bf(v);
        float x = ((m & 4095) < len) ? v : 0.f;
        colS[j] += x; colQ[j] += x * x;
      }
    }
  }
  #pragma unroll
  for (int j = 0; j < 4; ++j) {
    colS[j] += __shfl_xor(colS[j], 16); colS[j] += __shfl_xor(colS[j], 32);
    colQ[j] += __shfl_xor(colQ[j], 16); colQ[j] += __shfl_xor(colQ[j], 32);
    if (lane < 16) {
      int cl = wn + j * 16 + frow;
      atomicAdd(&lsum[cl], colS[j]);
      atomicAdd(&lsq[cl], colQ[j]);
    }
  }
  __syncthreads();
  if (tid < 128) {
    atomicAdd(&sums[n0 + tid], lsum[tid]);
    atomicAdd(&sums[384 + n0 + tid], lsq[tid]);
  }
}

// ---------------- BN finalize: per-channel scale/shift ----------------
__global__ void bn_finalize_kernel(const float* __restrict__ sums,
    const float* __restrict__ gamma, const float* __restrict__ beta,
    const int* __restrict__ lens, float* __restrict__ par)
{
  int c = threadIdx.x;  // 384
  float nv = 0.f;
  for (int b = 0; b < B_; ++b) nv += (float)lens[b];
  float mean = sums[c] / nv;
  float var = sums[384 + c] / nv - mean * mean;
  var = fmaxf(var, 0.f);
  float rstd = rsqrtf(var + 1e-5f);
  float a = rstd * gamma[c];
  par[c] = a;
  par[384 + c] = beta[c] - mean * a;
}

// ---------------- apply BN + GELU (in place on bf16 x0, masked) ----------------
__global__ __launch_bounds__(256) void apply_bn_gelu_kernel(
    u16* __restrict__ X, const float* __restrict__ par,
    const int* __restrict__ lens)
{
  int chunk = blockIdx.x * 256 + threadIdx.x;  // 65536*48 chunks of 8
  int row = chunk / 48;
  int c0 = (chunk - row * 48) * 8;
  int b = row >> 12, n = row & 4095;
  bool valid = n < lens[b];
  uint4 v = *(uint4*)(X + (size_t)row * D2_ + c0);
  u16* h = (u16*)&v;
  uint4 o;
  u16* ho = (u16*)&o;
  #pragma unroll
  for (int t = 0; t < 8; ++t) {
    float x = bf2f(h[t]);
    int c = c0 + t;
    float y = x * par[c] + par[384 + c];
    float g = 0.5f * y * (1.f + erf_approx(y * 0.70710678118654752f));
    ho[t] = valid ? f2bf(g) : (u16)0;
  }
  *(uint4*)(X + (size_t)row * D2_ + c0) = o;
}

// ---------------- apply BN (masked): bf16 x1 -> f32 out ----------------
__global__ __launch_bounds__(256) void apply_bn_out_kernel(
    const u16* __restrict__ X, const float* __restrict__ par,
    const int* __restrict__ lens, float* __restrict__ out)
{
  int chunk = blockIdx.x * 256 + threadIdx.x;  // 65536*48 chunks of 8
  int row = chunk / 48;
  int c0 = (chunk - row * 48) * 8;
  int b = row >> 12, n = row & 4095;
  bool valid = n < lens[b];
  uint4 v = *(const uint4*)(X + (size_t)row * D2_ + c0);
  u16* h = (u16*)&v;
  float tmp[8];
  #pragma unroll
  for (int t = 0; t < 8; ++t) {
    float x = bf2f(h[t]);
    int c = c0 + t;
    float y = x * par[c] + par[384 + c];
    tmp[t] = valid ? y : 0.f;
  }
  float4 o0 = make_float4(tmp[0], tmp[1], tmp[2], tmp[3]);
  float4 o1 = make_float4(tmp[4], tmp[5], tmp[6], tmp[7]);
  float* op = out + (size_t)row * D2_ + c0;
  *(float4*)op = o0;
  *(float4*)(op + 4) = o1;
}

extern "C" void kernel_launch(void* const* d_in, const int* in_sizes, int n_in,
                              void* d_out, int out_size, void* d_ws, size_t ws_size,
                              hipStream_t stream) {
  const float* xyz1    = (const float*)d_in[0];
  const float* xyz2    = (const float*)d_in[1];
  const float* points1 = (const float*)d_in[2];
  const float* points2 = (const float*)d_in[3];
  const int* point_lens = (const int*)d_in[4];
  const int* emb_lens   = (const int*)d_in[5];
  // d_in[6] = point_mask (recomputed from point_lens)
  const float* W0 = (const float*)d_in[7];
  const float* g0 = (const float*)d_in[8];
  const float* b0 = (const float*)d_in[9];
  const float* W1 = (const float*)d_in[10];
  const float* g1 = (const float*)d_in[11];
  const float* b1 = (const float*)d_in[12];

  float* out = (float*)d_out;
  float* idx_out = out + (size_t)M_ * D2_;   // idx tail (ints as floats)

  char* w = (char*)d_ws;
  u16* A1    = (u16*)w;                       // 65536 x 416 bf16 = 54,525,952 B
  u16* x1    = (u16*)w;                       // overlays A1 (dead after gemm1)
  u16* W0p   = (u16*)(w + 54525952);          // 384 x 416 bf16   =    319,488 B
  u16* W1c   = (u16*)(w + 54845440);          // 384 x 384 bf16   =    294,912 B
  u16* x0    = (u16*)(w + 55140352);          // 65536 x 384 bf16 = 50,331,648 B
  // wq/iq overlay x0 region (both dead before gemm1 writes x0)
  float* wq  = (float*)(w + 55140352);        // 65536 x 5 f32 = 1,310,720 B
  int*   iq  = (int*)(w + 56451072);          // 65536 x 5 i32 = 1,310,720 B
  float* stats = (float*)(w + 105472000);     // 1536 f32
  float* par   = (float*)(w + 105478144);     // 1536 f32

  zero_kernel<<<6, 256, 0, stream>>>(stats, 1536);
  pad_w0_kernel<<<624, 256, 0, stream>>>(W0, W0p);
  conv_w1_kernel<<<576, 256, 0, stream>>>(W1, W1c);
  knn_kernel<<<512, 256, 0, stream>>>(xyz1, xyz2, points1, emb_lens,
                                      A1, idx_out, wq, iq);
  interp_kernel<<<16384, 256, 0, stream>>>(points2, wq, iq, A1);
  gemm_nt_kernel<false><<<1536, 256, 0, stream>>>(
      A1, KP, W0p, KP, x0, D2_, 13, point_lens, stats);
  bn_finalize_kernel<<<1, 384, 0, stream>>>(stats, g0, b0, point_lens, par);
  apply_bn_gelu_kernel<<<12288, 256, 0, stream>>>(x0, par, point_lens);
  gemm_nt_kernel<false><<<1536, 256, 0, stream>>>(
      x0, D2_, W1c, D2_, x1, D2_, 12, point_lens, stats + 768);
  bn_finalize_kernel<<<1, 384, 0, stream>>>(stats + 768, g1, b1, point_lens, par + 768);
  apply_bn_out_kernel<<<12288, 256, 0, stream>>>(x1, par + 768, point_lens, out);
}